// Round 3
// baseline (423.023 us; speedup 1.0000x reference)
//
#include <hip/hip_runtime.h>
#include <hip/hip_bf16.h>

namespace {
constexpr int NB    = 64;
constexpr int V0d   = 40, V1d = 40, V2d = 200;
constexpr int NC0   = 5, NC1 = 5, NC2 = 21;
constexpr int CELLS = NC0 * NC1 * NC2;        // 525
constexpr int M     = NB * CELLS;             // 33600
constexpr int C1MAX = 104, C2MAX = 120;
constexpr int KS    = 104 * C1MAX * C2MAX;    // 1,297,920 dense compact keys
constexpr int SEG   = 4096;
constexpr int NSEG  = (KS + SEG - 1) / SEG;   // 317
constexpr int KSP   = NSEG * SEG;             // 1,298,432 (padded)
constexpr int CHVOL = 1000;
}

// Round through bf16 (expected outputs are bf16-rounded float32 values).
__device__ __forceinline__ float bf16r(float v) {
    return __bfloat162float(__float2bfloat16(v));
}

// compact dense index; strictly increasing in (c0,c1,c2) lexicographic order,
// identical ordering to the reference key (c0*65536 + c1*256 + c2).
__device__ __forceinline__ int enc(int c0, int c1, int c2) {
    return (c0 * C1MAX + c1) * C2MAX + c2;
}

__global__ void k_zero(int* __restrict__ P) {
    int idx = blockIdx.x * blockDim.x + threadIdx.x;
    int4* p4 = reinterpret_cast<int4*>(P);
    const int n4 = KSP / 4;
    for (int i = idx; i < n4; i += gridDim.x * blockDim.x)
        p4[i] = make_int4(0, 0, 0, 0);
}

__global__ void k_mark(const int* __restrict__ loc, int* __restrict__ P) {
    int m = blockIdx.x * blockDim.x + threadIdx.x;
    if (m >= M) return;
    int b = m / CELLS, cell = m % CELLS;
    int i = cell / (NC1 * NC2), j = (cell / NC2) % NC1, k = cell % NC2;
    P[enc(loc[b * 3 + 0] / 10 + i, loc[b * 3 + 1] / 10 + j,
          loc[b * 3 + 2] / 10 + k)] = 1;
}

// in-place exclusive scan of each SEG-sized segment; block totals -> Bsums
__global__ __launch_bounds__(256) void k_scan_blocks(int* __restrict__ P,
                                                     int* __restrict__ Bsums) {
    int bid = blockIdx.x, t = threadIdx.x;
    int4* p4 = reinterpret_cast<int4*>(P + (size_t)bid * SEG + t * 16);
    int4 a = p4[0], b = p4[1], c = p4[2], d = p4[3];
    int v[16] = {a.x, a.y, a.z, a.w, b.x, b.y, b.z, b.w,
                 c.x, c.y, c.z, c.w, d.x, d.y, d.z, d.w};
    int s = 0;
#pragma unroll
    for (int e = 0; e < 16; ++e) s += v[e];
    __shared__ int sc[256];
    sc[t] = s;
    __syncthreads();
#pragma unroll
    for (int off = 1; off < 256; off <<= 1) {
        int x = (t >= off) ? sc[t - off] : 0;
        __syncthreads();
        sc[t] += x;
        __syncthreads();
    }
    int incl = sc[t];
    if (t == 255) Bsums[bid] = incl;
    int run = incl - s;
#pragma unroll
    for (int e = 0; e < 16; ++e) { int x = v[e]; v[e] = run; run += x; }
    p4[0] = make_int4(v[0], v[1], v[2], v[3]);
    p4[1] = make_int4(v[4], v[5], v[6], v[7]);
    p4[2] = make_int4(v[8], v[9], v[10], v[11]);
    p4[3] = make_int4(v[12], v[13], v[14], v[15]);
}

// single-block exclusive scan of Bsums[NSEG]; total unique count -> U[0]
__global__ __launch_bounds__(256) void k_scan_sums(int* __restrict__ Bsums,
                                                   int* __restrict__ U) {
    __shared__ int sc[256];
    __shared__ int carry_s;
    int t = threadIdx.x;
    if (t == 0) carry_s = 0;
    __syncthreads();
    for (int base = 0; base < NSEG; base += 256) {
        int idx = base + t;
        int vv = (idx < NSEG) ? Bsums[idx] : 0;
        sc[t] = vv;
        __syncthreads();
#pragma unroll
        for (int off = 1; off < 256; off <<= 1) {
            int x = (t >= off) ? sc[t - off] : 0;
            __syncthreads();
            sc[t] += x;
            __syncthreads();
        }
        int incl = sc[t];
        int carry = carry_s;
        if (idx < NSEG) Bsums[idx] = carry + incl - vv;
        __syncthreads();
        if (t == 255) carry_s = carry + incl;
        __syncthreads();
    }
    if (t == 0) U[0] = carry_s;
}

__global__ void k_slots(const int* __restrict__ loc, const int* __restrict__ P,
                        const int* __restrict__ Bsums, int* __restrict__ ukeys) {
    int m = blockIdx.x * blockDim.x + threadIdx.x;
    if (m >= M) return;
    int b = m / CELLS, cell = m % CELLS;
    int i = cell / (NC1 * NC2), j = (cell / NC2) % NC1, k = cell % NC2;
    int d = enc(loc[b * 3 + 0] / 10 + i, loc[b * 3 + 1] / 10 + j,
                loc[b * 3 + 2] / 10 + k);
    int rank = P[d] + Bsums[d / SEG];  // global sorted position of this key
    ukeys[rank] = d;                    // same value from all writers
}

// one block per output slot; deterministic batch-ascending accumulation
__global__ __launch_bounds__(256) void k_out(const float* __restrict__ data,
                                             const int* __restrict__ loc,
                                             const int* __restrict__ ukeys,
                                             const int* __restrict__ U,
                                             float* __restrict__ out,
                                             long long out_lim) {
    int r = blockIdx.x;
    int t = threadIdx.x;
    __shared__ int sloc[NB * 3];
    __shared__ int skey, sU;
    if (t < NB * 3) sloc[t] = loc[t];
    if (t == 0) {
        int u = U[0];
        sU = u;
        skey = (r < u) ? ukeys[r] : -1;
    }
    __syncthreads();

    float acc[4] = {0.f, 0.f, 0.f, 0.f};
    if (r < sU && skey >= 0) {
        int d = skey;
        int c0 = d / (C1MAX * C2MAX);
        int rem = d % (C1MAX * C2MAX);
        int c1 = rem / C2MAX, c2 = rem % C2MAX;
        int g0 = c0 * 10, g1 = c1 * 10, g2 = c2 * 10;
        int ex[4], ey[4], ez[4];
#pragma unroll
        for (int q = 0; q < 4; ++q) {
            int e = t + 256 * q;
            ex[q] = e / 100; ey[q] = (e / 10) % 10; ez[q] = e % 10;
        }
        for (int b = 0; b < NB; ++b) {
            int l0 = sloc[b * 3 + 0], l1 = sloc[b * 3 + 1], l2 = sloc[b * 3 + 2];
            int i0 = c0 - l0 / 10, i1 = c1 - l1 / 10, i2 = c2 - l2 / 10;
            if ((unsigned)i0 < (unsigned)NC0 && (unsigned)i1 < (unsigned)NC1 &&
                (unsigned)i2 < (unsigned)NC2) {
                const float* db = data + (size_t)b * (V0d * V1d * V2d);
                int o0 = g0 - l0, o1 = g1 - l1, o2 = g2 - l2;
#pragma unroll
                for (int q = 0; q < 4; ++q) {
                    int e = t + 256 * q;
                    if (e < CHVOL) {
                        int p0 = o0 + ex[q], p1 = o1 + ey[q], p2 = o2 + ez[q];
                        if ((unsigned)p0 < (unsigned)V0d &&
                            (unsigned)p1 < (unsigned)V1d &&
                            (unsigned)p2 < (unsigned)V2d)
                            acc[q] += db[(p0 * V1d + p1) * V2d + p2];
                    }
                }
            }
        }
    }
#pragma unroll
    for (int q = 0; q < 4; ++q) {
        int e = t + 256 * q;
        long long idx = (long long)r * CHVOL + e;
        if (e < CHVOL && idx < out_lim)
            out[idx] = bf16r(acc[q]);
    }
}

__global__ void k_uloc(const int* __restrict__ ukeys, const int* __restrict__ U,
                       float* __restrict__ out,
                       long long base, long long out_sz) {
    int r = blockIdx.x * blockDim.x + threadIdx.x;
    if (r >= M) return;
    float u0, u1, u2;
    if (r < U[0]) {
        int d = ukeys[r];
        int c0 = d / (C1MAX * C2MAX);
        int rem = d % (C1MAX * C2MAX);
        u0 = (float)(c0 * 10);
        u1 = (float)((rem / C2MAX) * 10);
        u2 = (float)((rem % C2MAX) * 10);
    } else {  // jnp.unique fill 2^31-1 decoded: (327670, 2550, 2550)
        u0 = 327670.f; u1 = 2550.f; u2 = 2550.f;
    }
    long long i = base + (long long)r * 3;
    if (i + 2 < out_sz) {
        out[i + 0] = bf16r(u0);
        out[i + 1] = bf16r(u1);
        out[i + 2] = bf16r(u2);
    }
}

extern "C" void kernel_launch(void* const* d_in, const int* in_sizes, int n_in,
                              void* d_out, int out_size, void* d_ws, size_t ws_size,
                              hipStream_t stream) {
    const float* data = (const float*)d_in[0];
    const int* loc    = (const int*)d_in[1];
    float* out        = (float*)d_out;

    const size_t bytesP  = (size_t)KSP * 4;                               // 5.19 MB
    const size_t bytesSm = (size_t)(NSEG + 64) * 4 + (size_t)M * 4 + 64;  // ~136 KB

    char* ws = (char*)d_ws;
    int *P, *Bsums;
    if (ws_size >= bytesP + bytesSm) {
        P     = (int*)ws;
        Bsums = (int*)(ws + bytesP);
    } else {
        // Fallback: dense array lives in the head of output 0 (dead before
        // k_out, the only later writer of that region).
        P     = (int*)d_out;
        Bsums = (int*)ws;
    }
    int* ukeys = Bsums + NSEG + 64;
    int* U     = ukeys + M;

    long long out_sz   = (long long)out_size;               // 33,700,800 floats
    long long base_ul  = out_sz - (long long)3 * M;         // 33,600,000
    long long out0_lim = base_ul < (long long)M * CHVOL ? base_ul
                                                        : (long long)M * CHVOL;

    k_zero<<<640, 256, 0, stream>>>(P);
    k_mark<<<(M + 255) / 256, 256, 0, stream>>>(loc, P);
    k_scan_blocks<<<NSEG, 256, 0, stream>>>(P, Bsums);
    k_scan_sums<<<1, 256, 0, stream>>>(Bsums, U);
    k_slots<<<(M + 255) / 256, 256, 0, stream>>>(loc, P, Bsums, ukeys);
    k_out<<<M, 256, 0, stream>>>(data, loc, ukeys, U, out, out0_lim);
    k_uloc<<<(M + 255) / 256, 256, 0, stream>>>(ukeys, U, out, base_ul, out_sz);
}

// Round 4
// 70.694 us; speedup vs baseline: 5.9838x; 5.9838x over previous
//
#include <hip/hip_runtime.h>
#include <hip/hip_bf16.h>

namespace {
constexpr int NB    = 64;
constexpr int V0d   = 40, V1d = 40, V2d = 200;
constexpr int VOL   = V0d * V1d * V2d;        // 320,000
constexpr int NC0   = 5, NC1 = 5, NC2 = 21;
constexpr int CELLS = NC0 * NC1 * NC2;        // 525
constexpr int M     = NB * CELLS;             // 33600
constexpr int C1MAX = 104, C2MAX = 120;
constexpr int KS    = 104 * C1MAX * C2MAX;    // 1,297,920 dense compact keys
constexpr int SEG   = 4096;
constexpr int NSEG  = (KS + SEG - 1) / SEG;   // 317
constexpr int KSP   = NSEG * SEG;             // 1,298,432 (padded)
constexpr int CHVOL = 1000;
}

// Round through bf16 (expected outputs are bf16-rounded float32 values).
__device__ __forceinline__ float bf16r(float v) {
    return __bfloat162float(__float2bfloat16(v));
}

// compact dense index; strictly increasing in (c0,c1,c2) lexicographic order,
// identical ordering to the reference key (c0*65536 + c1*256 + c2).
__device__ __forceinline__ int enc(int c0, int c1, int c2) {
    return (c0 * C1MAX + c1) * C2MAX + c2;
}

__global__ void k_zero(int* __restrict__ P, int4* __restrict__ mask4) {
    int idx = blockIdx.x * blockDim.x + threadIdx.x;
    int stride = gridDim.x * blockDim.x;
    int4* p4 = reinterpret_cast<int4*>(P);
    const int n4 = KSP / 4;             // 324,608
    for (int i = idx; i < n4; i += stride) p4[i] = make_int4(0, 0, 0, 0);
    const int m4 = M * 8 / 16;          // 16,800 int4 covering mask[M] (u64)
    for (int i = idx; i < m4; i += stride) mask4[i] = make_int4(0, 0, 0, 0);
}

__global__ void k_mark(const int* __restrict__ loc, int* __restrict__ P) {
    int m = blockIdx.x * blockDim.x + threadIdx.x;
    if (m >= M) return;
    int b = m / CELLS, cell = m % CELLS;
    int i = cell / (NC1 * NC2), j = (cell / NC2) % NC1, k = cell % NC2;
    P[enc(loc[b * 3 + 0] / 10 + i, loc[b * 3 + 1] / 10 + j,
          loc[b * 3 + 2] / 10 + k)] = 1;
}

// in-place exclusive scan of each SEG-sized segment; block totals -> Bsums
__global__ __launch_bounds__(256) void k_scan_blocks(int* __restrict__ P,
                                                     int* __restrict__ Bsums) {
    int bid = blockIdx.x, t = threadIdx.x;
    int4* p4 = reinterpret_cast<int4*>(P + (size_t)bid * SEG + t * 16);
    int4 a = p4[0], b = p4[1], c = p4[2], d = p4[3];
    int v[16] = {a.x, a.y, a.z, a.w, b.x, b.y, b.z, b.w,
                 c.x, c.y, c.z, c.w, d.x, d.y, d.z, d.w};
    int s = 0;
#pragma unroll
    for (int e = 0; e < 16; ++e) s += v[e];
    __shared__ int sc[256];
    sc[t] = s;
    __syncthreads();
#pragma unroll
    for (int off = 1; off < 256; off <<= 1) {
        int x = (t >= off) ? sc[t - off] : 0;
        __syncthreads();
        sc[t] += x;
        __syncthreads();
    }
    int incl = sc[t];
    if (t == 255) Bsums[bid] = incl;
    int run = incl - s;
#pragma unroll
    for (int e = 0; e < 16; ++e) { int x = v[e]; v[e] = run; run += x; }
    p4[0] = make_int4(v[0], v[1], v[2], v[3]);
    p4[1] = make_int4(v[4], v[5], v[6], v[7]);
    p4[2] = make_int4(v[8], v[9], v[10], v[11]);
    p4[3] = make_int4(v[12], v[13], v[14], v[15]);
}

// single-block exclusive scan of Bsums[NSEG]; total unique count -> U[0]
__global__ __launch_bounds__(256) void k_scan_sums(int* __restrict__ Bsums,
                                                   int* __restrict__ U) {
    __shared__ int sc[256];
    __shared__ int carry_s;
    int t = threadIdx.x;
    if (t == 0) carry_s = 0;
    __syncthreads();
    for (int base = 0; base < NSEG; base += 256) {
        int idx = base + t;
        int vv = (idx < NSEG) ? Bsums[idx] : 0;
        sc[t] = vv;
        __syncthreads();
#pragma unroll
        for (int off = 1; off < 256; off <<= 1) {
            int x = (t >= off) ? sc[t - off] : 0;
            __syncthreads();
            sc[t] += x;
            __syncthreads();
        }
        int incl = sc[t];
        int carry = carry_s;
        if (idx < NSEG) Bsums[idx] = carry + incl - vv;
        __syncthreads();
        if (t == 255) carry_s = carry + incl;
        __syncthreads();
    }
    if (t == 0) U[0] = carry_s;
}

// rank every tile; record unique key per rank and the contributor batch mask
__global__ void k_slots(const int* __restrict__ loc, const int* __restrict__ P,
                        const int* __restrict__ Bsums, int* __restrict__ ukeys,
                        unsigned long long* __restrict__ mask) {
    int m = blockIdx.x * blockDim.x + threadIdx.x;
    if (m >= M) return;
    int b = m / CELLS, cell = m % CELLS;
    int i = cell / (NC1 * NC2), j = (cell / NC2) % NC1, k = cell % NC2;
    int d = enc(loc[b * 3 + 0] / 10 + i, loc[b * 3 + 1] / 10 + j,
                loc[b * 3 + 2] / 10 + k);
    int rank = P[d] + Bsums[d / SEG];   // global sorted position of this key
    ukeys[rank] = d;                     // same value from all writers
    atomicOr(&mask[rank], 1ull << b);    // order-independent -> deterministic
}

// one block per output slot; iterate only actual contributors (ascending b)
__global__ __launch_bounds__(256) void k_out(const float* __restrict__ data,
                                             const int* __restrict__ loc,
                                             const int* __restrict__ ukeys,
                                             const unsigned long long* __restrict__ mask,
                                             const int* __restrict__ U,
                                             float* __restrict__ out,
                                             long long base_ul) {
    // bijective XCD swizzle: M = 33600 = 8 * 4200 exactly
    int orig = blockIdx.x;
    int r = (orig & 7) * (M / 8) + (orig >> 3);
    int t = threadIdx.x;

    __shared__ int sloc[NB * 3];
    __shared__ int skey, sU;
    __shared__ unsigned long long smask;
    if (t < NB * 3) sloc[t] = loc[t];
    if (t == 0) {
        sU = U[0];
        skey = ukeys[r];
        smask = mask[r];
    }
    __syncthreads();

    bool valid = (r < sU);
    float acc[4] = {0.f, 0.f, 0.f, 0.f};
    int c0 = 0, c1 = 0, c2 = 0;
    if (valid) {
        int d = skey;
        c0 = d / (C1MAX * C2MAX);
        int rem = d % (C1MAX * C2MAX);
        c1 = rem / C2MAX;
        c2 = rem % C2MAX;
        int g0 = c0 * 10, g1 = c1 * 10, g2 = c2 * 10;
        int ex[4], ey[4], ez[4];
#pragma unroll
        for (int q = 0; q < 4; ++q) {
            int e = t + 256 * q;
            ex[q] = e / 100; ey[q] = (e / 10) % 10; ez[q] = e % 10;
        }
        unsigned long long mk = smask;
        while (mk) {
            int b = __builtin_ctzll(mk);
            mk &= mk - 1;
            int l0 = sloc[b * 3 + 0], l1 = sloc[b * 3 + 1], l2 = sloc[b * 3 + 2];
            const float* db = data + (size_t)b * VOL;
            int o0 = g0 - l0, o1 = g1 - l1, o2 = g2 - l2;
#pragma unroll
            for (int q = 0; q < 4; ++q) {
                int e = t + 256 * q;
                if (e < CHVOL) {
                    int p0 = o0 + ex[q], p1 = o1 + ey[q], p2 = o2 + ez[q];
                    if ((unsigned)p0 < (unsigned)V0d &&
                        (unsigned)p1 < (unsigned)V1d &&
                        (unsigned)p2 < (unsigned)V2d)
                        acc[q] += db[(p0 * V1d + p1) * V2d + p2];
                }
            }
        }
    }
#pragma unroll
    for (int q = 0; q < 4; ++q) {
        int e = t + 256 * q;
        if (e < CHVOL)
            out[(long long)r * CHVOL + e] = bf16r(acc[q]);
    }
    // fused uloc write (output 1)
    if (t == 0) {
        float u0, u1, u2;
        if (valid) {
            u0 = (float)(c0 * 10);
            u1 = (float)(c1 * 10);
            u2 = (float)(c2 * 10);
        } else {  // jnp.unique fill 2^31-1 decoded: (327670, 2550, 2550)
            u0 = 327670.f; u1 = 2550.f; u2 = 2550.f;
        }
        long long i = base_ul + (long long)r * 3;
        out[i + 0] = bf16r(u0);
        out[i + 1] = bf16r(u1);
        out[i + 2] = bf16r(u2);
    }
}

extern "C" void kernel_launch(void* const* d_in, const int* in_sizes, int n_in,
                              void* d_out, int out_size, void* d_ws, size_t ws_size,
                              hipStream_t stream) {
    const float* data = (const float*)d_in[0];
    const int* loc    = (const int*)d_in[1];
    float* out        = (float*)d_out;

    const size_t bytesP  = (size_t)KSP * 4;                         // 5.19 MB
    const size_t bytesSm = (size_t)M * 8                            // mask
                         + (size_t)(NSEG + 64) * 4                  // Bsums+pad
                         + (size_t)M * 4 + 64;                      // ukeys, U
                                                                    // ~405 KB
    char* ws = (char*)d_ws;
    int* P;
    char* smalls;
    if (ws_size >= bytesP + bytesSm) {
        P      = (int*)ws;
        smalls = ws + bytesP;
    } else {
        // Fallback: dense array lives in the head of output 0 (dead before
        // k_out, the only later writer of that region).
        P      = (int*)d_out;
        smalls = ws;
    }
    unsigned long long* mask = (unsigned long long*)smalls;         // 8B-aligned
    int* Bsums = (int*)(smalls + (size_t)M * 8);
    int* ukeys = Bsums + NSEG + 64;
    int* U     = ukeys + M;

    long long out_sz  = (long long)out_size;                // 33,700,800 floats
    long long base_ul = out_sz - (long long)3 * M;          // 33,600,000

    k_zero<<<640, 256, 0, stream>>>(P, (int4*)mask);
    k_mark<<<(M + 255) / 256, 256, 0, stream>>>(loc, P);
    k_scan_blocks<<<NSEG, 256, 0, stream>>>(P, Bsums);
    k_scan_sums<<<1, 256, 0, stream>>>(Bsums, U);
    k_slots<<<(M + 255) / 256, 256, 0, stream>>>(loc, P, Bsums, ukeys, mask);
    k_out<<<M, 256, 0, stream>>>(data, loc, ukeys, mask, U, out, base_ul);
}

// Round 5
// 63.758 us; speedup vs baseline: 6.6349x; 1.1088x over previous
//
#include <hip/hip_runtime.h>
#include <hip/hip_bf16.h>

namespace {
constexpr int NB    = 64;
constexpr int V0d   = 40, V1d = 40, V2d = 200;
constexpr int VOL   = V0d * V1d * V2d;        // 320,000
constexpr int NC0   = 5, NC1 = 5, NC2 = 21;
constexpr int CELLS = NC0 * NC1 * NC2;        // 525
constexpr int M     = NB * CELLS;             // 33600
constexpr int C1MAX = 104, C2MAX = 120;
constexpr int KS    = 104 * C1MAX * C2MAX;    // 1,297,920 dense compact keys
constexpr int SEG   = 4096;
constexpr int NSEG  = (KS + SEG - 1) / SEG;   // 317
constexpr int KSP   = NSEG * SEG;             // 1,298,432 (padded)
constexpr int CHVOL = 1000;
}

// Round through bf16 (expected outputs are bf16-rounded float32 values).
__device__ __forceinline__ float bf16r(float v) {
    return __bfloat162float(__float2bfloat16(v));
}

// compact dense index; strictly increasing in (c0,c1,c2) lexicographic order,
// identical ordering to the reference key (c0*65536 + c1*256 + c2).
__device__ __forceinline__ int enc(int c0, int c1, int c2) {
    return (c0 * C1MAX + c1) * C2MAX + c2;
}

__global__ void k_zero(int* __restrict__ P, int4* __restrict__ mask4) {
    int idx = blockIdx.x * blockDim.x + threadIdx.x;
    int stride = gridDim.x * blockDim.x;
    int4* p4 = reinterpret_cast<int4*>(P);
    const int n4 = KSP / 4;             // 324,608
    for (int i = idx; i < n4; i += stride) p4[i] = make_int4(0, 0, 0, 0);
    const int m4 = M * 8 / 16;          // 16,800 int4 covering mask[M] (u64)
    for (int i = idx; i < m4; i += stride) mask4[i] = make_int4(0, 0, 0, 0);
}

__global__ void k_mark(const int* __restrict__ loc, int* __restrict__ P) {
    int m = blockIdx.x * blockDim.x + threadIdx.x;
    if (m >= M) return;
    int b = m / CELLS, cell = m % CELLS;
    int i = cell / (NC1 * NC2), j = (cell / NC2) % NC1, k = cell % NC2;
    P[enc(loc[b * 3 + 0] / 10 + i, loc[b * 3 + 1] / 10 + j,
          loc[b * 3 + 2] / 10 + k)] = 1;
}

// in-place exclusive scan of each SEG-sized segment; block totals -> Bsums
__global__ __launch_bounds__(256) void k_scan_blocks(int* __restrict__ P,
                                                     int* __restrict__ Bsums) {
    int bid = blockIdx.x, t = threadIdx.x;
    int4* p4 = reinterpret_cast<int4*>(P + (size_t)bid * SEG + t * 16);
    int4 a = p4[0], b = p4[1], c = p4[2], d = p4[3];
    int v[16] = {a.x, a.y, a.z, a.w, b.x, b.y, b.z, b.w,
                 c.x, c.y, c.z, c.w, d.x, d.y, d.z, d.w};
    int s = 0;
#pragma unroll
    for (int e = 0; e < 16; ++e) s += v[e];
    __shared__ int sc[256];
    sc[t] = s;
    __syncthreads();
#pragma unroll
    for (int off = 1; off < 256; off <<= 1) {
        int x = (t >= off) ? sc[t - off] : 0;
        __syncthreads();
        sc[t] += x;
        __syncthreads();
    }
    int incl = sc[t];
    if (t == 255) Bsums[bid] = incl;
    int run = incl - s;
#pragma unroll
    for (int e = 0; e < 16; ++e) { int x = v[e]; v[e] = run; run += x; }
    p4[0] = make_int4(v[0], v[1], v[2], v[3]);
    p4[1] = make_int4(v[4], v[5], v[6], v[7]);
    p4[2] = make_int4(v[8], v[9], v[10], v[11]);
    p4[3] = make_int4(v[12], v[13], v[14], v[15]);
}

// single-block exclusive scan of Bsums[NSEG]; total unique count -> U[0]
__global__ __launch_bounds__(256) void k_scan_sums(int* __restrict__ Bsums,
                                                   int* __restrict__ U) {
    __shared__ int sc[256];
    __shared__ int carry_s;
    int t = threadIdx.x;
    if (t == 0) carry_s = 0;
    __syncthreads();
    for (int base = 0; base < NSEG; base += 256) {
        int idx = base + t;
        int vv = (idx < NSEG) ? Bsums[idx] : 0;
        sc[t] = vv;
        __syncthreads();
#pragma unroll
        for (int off = 1; off < 256; off <<= 1) {
            int x = (t >= off) ? sc[t - off] : 0;
            __syncthreads();
            sc[t] += x;
            __syncthreads();
        }
        int incl = sc[t];
        int carry = carry_s;
        if (idx < NSEG) Bsums[idx] = carry + incl - vv;
        __syncthreads();
        if (t == 255) carry_s = carry + incl;
        __syncthreads();
    }
    if (t == 0) U[0] = carry_s;
}

// rank every tile; record unique key per rank and the contributor batch mask
__global__ void k_slots(const int* __restrict__ loc, const int* __restrict__ P,
                        const int* __restrict__ Bsums, int* __restrict__ ukeys,
                        unsigned long long* __restrict__ mask) {
    int m = blockIdx.x * blockDim.x + threadIdx.x;
    if (m >= M) return;
    int b = m / CELLS, cell = m % CELLS;
    int i = cell / (NC1 * NC2), j = (cell / NC2) % NC1, k = cell % NC2;
    int d = enc(loc[b * 3 + 0] / 10 + i, loc[b * 3 + 1] / 10 + j,
                loc[b * 3 + 2] / 10 + k);
    int rank = P[d] + Bsums[d / SEG];   // global sorted position of this key
    ukeys[rank] = d;                     // same value from all writers
    atomicOr(&mask[rank], 1ull << b);    // order-independent -> deterministic
}

// one block per output slot. No LDS, no barrier: every block-level value is
// wave-uniform (blockIdx-derived) -> compiler scalarizes to s_loads.
// Thread t<250 owns float4 group [4t..4t+3] of the 1000-elem chunk.
__global__ __launch_bounds__(256) void k_out(const float* __restrict__ data,
                                             const int* __restrict__ loc,
                                             const int* __restrict__ ukeys,
                                             const unsigned long long* __restrict__ mask,
                                             const int* __restrict__ U,
                                             float* __restrict__ out,
                                             long long base_ul) {
    // bijective XCD swizzle: M = 33600 = 8 * 4200 exactly
    int orig = blockIdx.x;
    int r = (orig & 7) * (M / 8) + (orig >> 3);
    int t = threadIdx.x;

    bool valid = (r < U[0]);
    float ax = 0.f, ay = 0.f, az = 0.f, aw = 0.f;
    int c0 = 0, c1 = 0, c2 = 0;

    if (valid) {
        int d = ukeys[r];                       // uniform -> s_load
        c0 = d / (C1MAX * C2MAX);
        int rem = d % (C1MAX * C2MAX);
        c1 = rem / C2MAX;
        c2 = rem % C2MAX;
        if (t < 250) {
            int e0 = t * 4;
            int x  = e0 / 100;
            int rm = e0 % 100;
            int y  = rm / 10;
            int z0 = rm % 10;                   // in {0,2,4,6,8}
            int g0 = c0 * 10, g1 = c1 * 10, g2 = c2 * 10;
            unsigned long long mk = mask[r];    // uniform -> s_load
            while (mk) {                        // ascending b == numpy order
                int b = __builtin_ctzll(mk);
                mk &= mk - 1;
                int l0 = loc[b * 3 + 0];        // uniform -> s_load
                int l1 = loc[b * 3 + 1];
                int l2 = loc[b * 3 + 2];
                const float* db = data + (size_t)b * VOL;
                if (z0 <= 6) {
                    // all 4 elems share one source row (x,y)
                    int p0 = g0 - l0 + x, p1 = g1 - l1 + y, p2 = g2 - l2 + z0;
                    if ((unsigned)p0 < (unsigned)V0d &&
                        (unsigned)p1 < (unsigned)V1d) {
                        const float* s = db + (p0 * V1d + p1) * V2d + p2;
                        if (p2 >= 0 && p2 <= V2d - 4) {
                            ax += s[0]; ay += s[1]; az += s[2]; aw += s[3];
                        } else {
                            if ((unsigned)p2       < (unsigned)V2d) ax += s[0];
                            if ((unsigned)(p2 + 1) < (unsigned)V2d) ay += s[1];
                            if ((unsigned)(p2 + 2) < (unsigned)V2d) az += s[2];
                            if ((unsigned)(p2 + 3) < (unsigned)V2d) aw += s[3];
                        }
                    }
                } else {
                    // z0 == 8: group straddles a y-row boundary; per-element
                    float av[4] = {0.f, 0.f, 0.f, 0.f};
#pragma unroll
                    for (int j = 0; j < 4; ++j) {
                        int e  = e0 + j;
                        int xx = e / 100;
                        int rj = e % 100;
                        int yy = rj / 10, zz = rj % 10;
                        int q0 = g0 - l0 + xx, q1 = g1 - l1 + yy,
                            q2 = g2 - l2 + zz;
                        if ((unsigned)q0 < (unsigned)V0d &&
                            (unsigned)q1 < (unsigned)V1d &&
                            (unsigned)q2 < (unsigned)V2d)
                            av[j] = db[(q0 * V1d + q1) * V2d + q2];
                    }
                    ax += av[0]; ay += av[1]; az += av[2]; aw += av[3];
                }
            }
        }
    }

    if (t < 250) {
        // out + r*1000 floats = r*4000 B (16B aligned); +t*16 B -> aligned
        *reinterpret_cast<float4*>(out + (long long)r * CHVOL + t * 4) =
            make_float4(bf16r(ax), bf16r(ay), bf16r(az), bf16r(aw));
    }
    if (t == 0) {  // fused uloc write (output 1)
        float u0, u1, u2;
        if (valid) {
            u0 = (float)(c0 * 10);
            u1 = (float)(c1 * 10);
            u2 = (float)(c2 * 10);
        } else {  // jnp.unique fill 2^31-1 decoded: (327670, 2550, 2550)
            u0 = 327670.f; u1 = 2550.f; u2 = 2550.f;
        }
        long long i = base_ul + (long long)r * 3;
        out[i + 0] = bf16r(u0);
        out[i + 1] = bf16r(u1);
        out[i + 2] = bf16r(u2);
    }
}

extern "C" void kernel_launch(void* const* d_in, const int* in_sizes, int n_in,
                              void* d_out, int out_size, void* d_ws, size_t ws_size,
                              hipStream_t stream) {
    const float* data = (const float*)d_in[0];
    const int* loc    = (const int*)d_in[1];
    float* out        = (float*)d_out;

    const size_t bytesP  = (size_t)KSP * 4;                         // 5.19 MB
    const size_t bytesSm = (size_t)M * 8                            // mask
                         + (size_t)(NSEG + 64) * 4                  // Bsums+pad
                         + (size_t)M * 4 + 64;                      // ukeys, U
                                                                    // ~405 KB
    char* ws = (char*)d_ws;
    int* P;
    char* smalls;
    if (ws_size >= bytesP + bytesSm) {
        P      = (int*)ws;
        smalls = ws + bytesP;
    } else {
        // Fallback: dense array lives in the head of output 0 (dead before
        // k_out, the only later writer of that region).
        P      = (int*)d_out;
        smalls = ws;
    }
    unsigned long long* mask = (unsigned long long*)smalls;         // 8B-aligned
    int* Bsums = (int*)(smalls + (size_t)M * 8);
    int* ukeys = Bsums + NSEG + 64;
    int* U     = ukeys + M;

    long long out_sz  = (long long)out_size;                // 33,700,800 floats
    long long base_ul = out_sz - (long long)3 * M;          // 33,600,000

    k_zero<<<640, 256, 0, stream>>>(P, (int4*)mask);
    k_mark<<<(M + 255) / 256, 256, 0, stream>>>(loc, P);
    k_scan_blocks<<<NSEG, 256, 0, stream>>>(P, Bsums);
    k_scan_sums<<<1, 256, 0, stream>>>(Bsums, U);
    k_slots<<<(M + 255) / 256, 256, 0, stream>>>(loc, P, Bsums, ukeys, mask);
    k_out<<<M, 256, 0, stream>>>(data, loc, ukeys, mask, U, out, base_ul);
}